// Round 15
// baseline (651.005 us; speedup 1.0000x reference)
//
#include <hip/hip_runtime.h>
#include <stdint.h>

// EISepLSTM: x(T,B,I) -> ig GEMM -> 512-step EI recurrence -> out GEMM.
// T=512, B=128, I=H=O=512.
// Round 15: r14 + deferred hs store. h[t] is held in a register and stored
// at the TOP of step t+1 (right after the barrier) so the store completes
// during the step and the end-of-step __syncthreads vmcnt drain never
// stalls on it. As byte-store issued immediately after a is computed.
// Everything else identical to replay-stable r14.

typedef __attribute__((ext_vector_type(8))) short short8;
typedef __attribute__((ext_vector_type(4))) float f32x4;
typedef __attribute__((ext_vector_type(4))) int int4x;

__device__ __forceinline__ unsigned short f2b(float f) {
  unsigned int u = __float_as_uint(f);
  u = (u + 0x7fffu + ((u >> 16) & 1u)) >> 16;   // RNE
  return (unsigned short)u;
}
__device__ __forceinline__ float b2f(unsigned short s) {
  return __uint_as_float(((unsigned int)s) << 16);
}

// ---------------- prep: ei (plain), bf16 weight casts, c_last zeros --------
__global__ void prep_kernel(const float* __restrict__ gu,      // (T,H,2)
                            const float* __restrict__ logit,   // (H,2)
                            const float* __restrict__ win,     // (H,I)
                            const float* __restrict__ wout,    // (O,H)
                            float* __restrict__ ei,            // (T,H)
                            unsigned short* __restrict__ winb,
                            unsigned short* __restrict__ woutb,
                            float* __restrict__ c_last) {
  int i = blockIdx.x * 256 + threadIdx.x;          // 0 .. 262143
  int h = i & 511;
  float u0 = gu[2 * i], u1 = gu[2 * i + 1];
  float l0 = logit[2 * h], l1 = logit[2 * h + 1];
  float g0 = -logf(-logf(u0 + 1e-10f) + 1e-10f);
  float g1 = -logf(-logf(u1 + 1e-10f) + 1e-10f);
  // softmax2 diff == tanh(dz/2), dz = ((l0+g0)-(l1+g1))/tau
  float dz = ((l0 + g0) - (l1 + g1)) * 10.0f;
  ei[i] = tanhf(0.5f * dz);
  winb[i]  = f2b(win[i]);
  woutb[i] = f2b(wout[i]);
  if (i < 65536) c_last[i] = 0.0f;
}

// ---------------- Wrec row quantization: i8 with per-row scale -------------
__global__ void wquant_kernel(const float* __restrict__ wrec,  // (H,H)
                              char* __restrict__ wrec8,        // (H,H) i8
                              float* __restrict__ wscale) {    // (H)
  const int n = blockIdx.x;          // output row 0..511
  const int l = threadIdx.x;         // 0..63
  const float* row = wrec + (size_t)n * 512 + l * 8;
  float v[8];
  float m = 0.f;
#pragma unroll
  for (int e = 0; e < 8; ++e) {
    v[e] = fmaxf(row[e], 0.f);
    m = fmaxf(m, v[e]);
  }
#pragma unroll
  for (int off = 32; off >= 1; off >>= 1) m = fmaxf(m, __shfl_down(m, off));
  m = __shfl(m, 0);
  const float s = (m > 0.f) ? (m / 127.f) : 1.f;
  const float inv = 1.f / s;
  unsigned long long pk = 0;
#pragma unroll
  for (int e = 0; e < 8; ++e) {
    int q = (int)rintf(v[e] * inv);
    pk |= ((unsigned long long)(unsigned char)(char)q) << (8 * e);
  }
  *(unsigned long long*)(wrec8 + (size_t)n * 512 + l * 8) = pk;
  if (l == 0) wscale[n] = s;
}

// ---------------- GEMM: C[m,n] = sum_k A[m,k]*W[n,k] + bias[n] -------------
// A: M x 512 (f32 or bf16), W: 512 x 512 bf16 row-major, out f32 or bf16.
template <int A_F32, int OUT_BF16>
__global__ __launch_bounds__(256, 2) void gemm512(
    const void* __restrict__ Ap, const unsigned short* __restrict__ W,
    const float* __restrict__ bias, void* __restrict__ Cp) {
  __shared__ __align__(16) unsigned short Al[128][32];
  __shared__ __align__(16) unsigned short Bl[128][32];
  const int tid = threadIdx.x;
  const int w = tid >> 6, l = tid & 63;
  const int wr = w >> 1, wc = w & 1;
  const int lm = l & 15, lq = l >> 4;
  const size_t m0 = (size_t)blockIdx.x * 128;
  const int n0 = blockIdx.y * 128;
  const int r = tid >> 1;             // staging row 0..127
  const int sb = (tid & 1) << 1;      // staging slot base (16B slots): 0 or 2
  f32x4 acc[4][4] = {};

  for (int kt = 0; kt < 16; ++kt) {
    const int k0 = kt << 5;
    // stage A tile
    {
      char* dst = (char*)Al + r * 64;
      if (A_F32) {
        const float* A = (const float*)Ap + (m0 + r) * 512 + k0 + (sb << 3);
#pragma unroll
        for (int j = 0; j < 2; ++j) {
          float4 v0 = ((const float4*)A)[2 * j + 0];
          float4 v1 = ((const float4*)A)[2 * j + 1];
          short8 o;
          o[0] = (short)f2b(v0.x); o[1] = (short)f2b(v0.y);
          o[2] = (short)f2b(v0.z); o[3] = (short)f2b(v0.w);
          o[4] = (short)f2b(v1.x); o[5] = (short)f2b(v1.y);
          o[6] = (short)f2b(v1.z); o[7] = (short)f2b(v1.w);
          *(short8*)(dst + (((sb + j + (r >> 1)) & 3) << 4)) = o;
        }
      } else {
        const unsigned short* A =
            (const unsigned short*)Ap + (m0 + r) * 512 + k0 + (sb << 3);
#pragma unroll
        for (int j = 0; j < 2; ++j)
          *(short8*)(dst + (((sb + j + (r >> 1)) & 3) << 4)) =
              *(const short8*)(A + 8 * j);
      }
      // stage W tile
      const unsigned short* Wp = W + ((size_t)(n0 + r) << 9) + k0 + (sb << 3);
      char* dstB = (char*)Bl + r * 64;
#pragma unroll
      for (int j = 0; j < 2; ++j)
        *(short8*)(dstB + (((sb + j + (r >> 1)) & 3) << 4)) =
            *(const short8*)(Wp + 8 * j);
    }
    __syncthreads();
    short8 af[4], bf[4];
#pragma unroll
    for (int i = 0; i < 4; ++i) {
      int row = wr * 64 + i * 16 + lm;
      af[i] = *(const short8*)((char*)Al + row * 64 +
                               (((lq + (row >> 1)) & 3) << 4));
    }
#pragma unroll
    for (int j = 0; j < 4; ++j) {
      int row = wc * 64 + j * 16 + lm;
      bf[j] = *(const short8*)((char*)Bl + row * 64 +
                               (((lq + (row >> 1)) & 3) << 4));
    }
#pragma unroll
    for (int i = 0; i < 4; ++i)
#pragma unroll
      for (int j = 0; j < 4; ++j)
        acc[i][j] =
            __builtin_amdgcn_mfma_f32_16x16x32_bf16(af[i], bf[j], acc[i][j], 0, 0, 0);
    __syncthreads();
  }
  float bv[4];
#pragma unroll
  for (int j = 0; j < 4; ++j) bv[j] = bias[n0 + wc * 64 + j * 16 + lm];
#pragma unroll
  for (int i = 0; i < 4; ++i) {
#pragma unroll
    for (int r4 = 0; r4 < 4; ++r4) {
      size_t gm = m0 + wr * 64 + i * 16 + lq * 4 + r4;
#pragma unroll
      for (int j = 0; j < 4; ++j) {
        int gn = n0 + wc * 64 + j * 16 + lm;
        float v = acc[i][j][r4] + bv[j];
        if (OUT_BF16)
          ((unsigned short*)Cp)[(gm << 9) + gn] = f2b(v);
        else
          ((float*)Cp)[(gm << 9) + gn] = v;
      }
    }
  }
}

// ---------------- recurrence (M=1, i8 MFMA, single-row A, deferred hs) -----
// block g: batch row g. wave w: cols [64w,64w+64) = 4 j-tiles; weights
// bregs[8][4] (AGPR-resident, MFMA-native). As[2][512] i8: only lm==0 lanes
// read (A row 0); rows 1..15 fed zeros. acc[j][0] (lq==0 lanes) -> Rls ->
// epilogue 1 col/lane (n = tid). hs[t] stored at top of step t+1.
__global__ __launch_bounds__(512, 1) void recur15_kernel(
    const unsigned short* __restrict__ ig,   // (T*B,512) bf16 plain
    const float* __restrict__ ei,            // (T,512) f32 plain
    const char* __restrict__ wrec8,          // (H,H) i8
    const float* __restrict__ wscale,        // (H)
    const float* __restrict__ rbias,         // (H)
    unsigned short* __restrict__ hs,         // (T*B,512) bf16 plain
    float* __restrict__ h_last) {            // (B,H) f32
  __shared__ __align__(16) char As[2][512];  // 1 KB
  __shared__ float Rls[8][68];               // 2.2 KB
  const int tid = threadIdx.x;
  const int g = blockIdx.x;            // batch row
  const int w = tid >> 6, l = tid & 63;
  const int lm = l & 15, lq = l >> 4;
  const int nbase = w << 6;
  const int n_own = nbase + l;         // == tid; this lane's output column
  const bool lmz = (lm == 0);

  // weights: bregs[kk][j] = Wrec8[nbase+j*16+lm][kk*64+lq*16 .. +16]
  int4x bregs[8][4];
#pragma unroll
  for (int kk = 0; kk < 8; ++kk)
#pragma unroll
    for (int j = 0; j < 4; ++j)
      bregs[kk][j] = *(const int4x*)(
          wrec8 + ((size_t)(nbase + j * 16 + lm) << 9) + (kk << 6) + (lq << 4));
  const float wscv = wscale[n_own] * 0.0625f;   // * (1/16) a-scale
  const float rbv  = rbias[n_own];
  // zero both As parities (h0 = 0)
  if (tid < 256) ((int*)As)[tid] = 0;
  __syncthreads();

  // register double-buffer of ig[t] / ei[t+1]
  const unsigned short* igp = ig + ((size_t)g << 9) + n_own; // t-stride 65536
  unsigned short ig_cur = igp[0];
  float ei_cur = ei[512 + n_own];
  unsigned short h_prev = 0;           // hs value of step t-1 (deferred store)
  float h_fin = 0.f;                   // final h (t=511) for h_last

  unsigned short* hsp = hs + ((size_t)g << 9) + n_own;       // t-stride 65536

#pragma unroll 1
  for (int t = 0; t < 512; ++t) {
    const int par = t & 1, par2 = par ^ 1;
    // deferred hs store for step t-1 (completes during this step)
    if (t > 0)
      __builtin_nontemporal_store(h_prev, hsp + (size_t)(t - 1) * 65536);
    // prefetch next step (consumed next iteration; hides under MFMAs)
    unsigned short ig_nxt = 0;
    float ei_nxt = 0.f;
    if (t < 511)
      ig_nxt = __builtin_nontemporal_load(igp + (size_t)(t + 1) * 65536);
    if (t < 510) ei_nxt = ei[(size_t)(t + 2) * 512 + n_own];

    // K-loop: A row 0 = a_t, rows 1..15 zero. 8 chains of 4 for latency.
    int4x accA[4] = {}, accB[4] = {};
    const char* ap = &As[par][0];
#pragma unroll
    for (int kk = 0; kk < 8; kk += 2) {
      int4x av0 = {0, 0, 0, 0}, av1 = {0, 0, 0, 0};
      if (lmz) {
        av0 = *(const int4x*)(ap + ((kk + 0) << 6) + (lq << 4));
        av1 = *(const int4x*)(ap + ((kk + 1) << 6) + (lq << 4));
      }
#pragma unroll
      for (int j = 0; j < 4; ++j) {
        accA[j] = __builtin_amdgcn_mfma_i32_16x16x64_i8(av0, bregs[kk][j],
                                                        accA[j], 0, 0, 0);
        accB[j] = __builtin_amdgcn_mfma_i32_16x16x64_i8(av1, bregs[kk + 1][j],
                                                        accB[j], 0, 0, 0);
      }
    }
    // redistribute: valid value (accA+accB)[j][0] lives in lq==0 lanes
    if (lq == 0) {
#pragma unroll
      for (int j = 0; j < 4; ++j)
        Rls[w][j * 17 + lm] = (float)(accA[j][0] + accB[j][0]);
    }
    // same-wave LDS write->read: ordered via lgkmcnt
    float rec = Rls[w][lq * 17 + lm] * wscv;
    float z = rec + b2f(ig_cur) + rbv;
    // fast softplus: max(z,0) + log(1+exp(-|z|)), native exp/log
    float az = fabsf(z);
    float h = fmaxf(z, 0.f) + __logf(1.f + __expf(-az));
    if (t < 511) {
      // critical path first: a_{t+1} into LDS (only needs lgkm drain)
      float a = h * ei_cur * 16.f;
      int ai = (int)rintf(fminf(fmaxf(a, -127.f), 127.f));
      As[par2][n_own] = (char)ai;   // coalesced byte store
    } else {
      h_fin = h;
    }
    h_prev = f2b(h);                // store next iteration (or post-loop)
    ig_cur = ig_nxt;
    ei_cur = ei_nxt;
    __syncthreads();   // As[par2] visible before next step's K-loop
  }
  // tail: hs[511] and h_last
  __builtin_nontemporal_store(h_prev, hsp + (size_t)511 * 65536);
  h_last[((size_t)g << 9) + n_own] = h_fin;
}

// ---------------- launch ---------------------------------------------------
extern "C" void kernel_launch(void* const* d_in, const int* in_sizes, int n_in,
                              void* d_out, int out_size, void* d_ws,
                              size_t ws_size, hipStream_t stream) {
  const float* x     = (const float*)d_in[0];
  const float* gu    = (const float*)d_in[1];
  const float* Win   = (const float*)d_in[2];
  const float* bin   = (const float*)d_in[3];
  const float* Wrec  = (const float*)d_in[4];
  const float* rbias = (const float*)d_in[5];
  const float* elog  = (const float*)d_in[6];
  const float* Wout  = (const float*)d_in[7];
  const float* bout  = (const float*)d_in[8];

  char* ws = (char*)d_ws;
  float* ei             = (float*)ws;                        // 1 MB
  unsigned short* winb  = (unsigned short*)(ws + 4194304);   // 512 KB
  unsigned short* woutb = (unsigned short*)(ws + 4718592);   // 512 KB
  char* wrec8           = (char*)(ws + 5242880);             // 256 KB
  float* wscale         = (float*)(ws + 5505024);            // 2 KB
  unsigned short* igb   = (unsigned short*)(ws + 6291456);   // 64 MB
  unsigned short* hs    = (unsigned short*)(ws + 73400320);  // 64 MB

  float* outp  = (float*)d_out;            // (T,B,O) f32
  float* hlast = outp + 33554432;          // (B,H)
  float* clast = outp + 33554432 + 65536;  // (B,H) zeros

  prep_kernel<<<1024, 256, 0, stream>>>(gu, elog, Win, Wout, ei, winb, woutb,
                                        clast);
  wquant_kernel<<<512, 64, 0, stream>>>(Wrec, wrec8, wscale);
  gemm512<1, 1><<<dim3(512, 4), 256, 0, stream>>>(x, winb, bin, igb);
  recur15_kernel<<<128, 512, 0, stream>>>(igb, ei, wrec8, wscale, rbias, hs,
                                          hlast);
  gemm512<0, 0><<<dim3(512, 4), 256, 0, stream>>>(hs, woutb, bout, outp);
}

// Round 16
// 581.776 us; speedup vs baseline: 1.1190x; 1.1190x over previous
//
#include <hip/hip_runtime.h>
#include <stdint.h>

// EISepLSTM: x(T,B,I) -> ig GEMM -> 512-step EI recurrence -> out GEMM.
// T=512, B=128, I=H=O=512.
// Round 16: r14 (replay-stable base) with VALU fat removed:
//  - 4 MFMA chains of 8 (was 8 of 4): half the acc zero-init, no merge adds.
//  - shuffle redistribute: __shfl(acc[j][0], lm) + cndmask select replaces
//    the Rls LDS round-trip (epilogue no longer waits on lgkm for it).
//  - hs stored immediately (r14 placement; r15's deferral regressed).
// Everything else byte-identical to r14.

typedef __attribute__((ext_vector_type(8))) short short8;
typedef __attribute__((ext_vector_type(4))) float f32x4;
typedef __attribute__((ext_vector_type(4))) int int4x;

__device__ __forceinline__ unsigned short f2b(float f) {
  unsigned int u = __float_as_uint(f);
  u = (u + 0x7fffu + ((u >> 16) & 1u)) >> 16;   // RNE
  return (unsigned short)u;
}
__device__ __forceinline__ float b2f(unsigned short s) {
  return __uint_as_float(((unsigned int)s) << 16);
}

// ---------------- prep: ei (plain), bf16 weight casts, c_last zeros --------
__global__ void prep_kernel(const float* __restrict__ gu,      // (T,H,2)
                            const float* __restrict__ logit,   // (H,2)
                            const float* __restrict__ win,     // (H,I)
                            const float* __restrict__ wout,    // (O,H)
                            float* __restrict__ ei,            // (T,H)
                            unsigned short* __restrict__ winb,
                            unsigned short* __restrict__ woutb,
                            float* __restrict__ c_last) {
  int i = blockIdx.x * 256 + threadIdx.x;          // 0 .. 262143
  int h = i & 511;
  float u0 = gu[2 * i], u1 = gu[2 * i + 1];
  float l0 = logit[2 * h], l1 = logit[2 * h + 1];
  float g0 = -logf(-logf(u0 + 1e-10f) + 1e-10f);
  float g1 = -logf(-logf(u1 + 1e-10f) + 1e-10f);
  // softmax2 diff == tanh(dz/2), dz = ((l0+g0)-(l1+g1))/tau
  float dz = ((l0 + g0) - (l1 + g1)) * 10.0f;
  ei[i] = tanhf(0.5f * dz);
  winb[i]  = f2b(win[i]);
  woutb[i] = f2b(wout[i]);
  if (i < 65536) c_last[i] = 0.0f;
}

// ---------------- Wrec row quantization: i8 with per-row scale -------------
__global__ void wquant_kernel(const float* __restrict__ wrec,  // (H,H)
                              char* __restrict__ wrec8,        // (H,H) i8
                              float* __restrict__ wscale) {    // (H)
  const int n = blockIdx.x;          // output row 0..511
  const int l = threadIdx.x;         // 0..63
  const float* row = wrec + (size_t)n * 512 + l * 8;
  float v[8];
  float m = 0.f;
#pragma unroll
  for (int e = 0; e < 8; ++e) {
    v[e] = fmaxf(row[e], 0.f);
    m = fmaxf(m, v[e]);
  }
#pragma unroll
  for (int off = 32; off >= 1; off >>= 1) m = fmaxf(m, __shfl_down(m, off));
  m = __shfl(m, 0);
  const float s = (m > 0.f) ? (m / 127.f) : 1.f;
  const float inv = 1.f / s;
  unsigned long long pk = 0;
#pragma unroll
  for (int e = 0; e < 8; ++e) {
    int q = (int)rintf(v[e] * inv);
    pk |= ((unsigned long long)(unsigned char)(char)q) << (8 * e);
  }
  *(unsigned long long*)(wrec8 + (size_t)n * 512 + l * 8) = pk;
  if (l == 0) wscale[n] = s;
}

// ---------------- GEMM: C[m,n] = sum_k A[m,k]*W[n,k] + bias[n] -------------
// A: M x 512 (f32 or bf16), W: 512 x 512 bf16 row-major, out f32 or bf16.
template <int A_F32, int OUT_BF16>
__global__ __launch_bounds__(256, 2) void gemm512(
    const void* __restrict__ Ap, const unsigned short* __restrict__ W,
    const float* __restrict__ bias, void* __restrict__ Cp) {
  __shared__ __align__(16) unsigned short Al[128][32];
  __shared__ __align__(16) unsigned short Bl[128][32];
  const int tid = threadIdx.x;
  const int w = tid >> 6, l = tid & 63;
  const int wr = w >> 1, wc = w & 1;
  const int lm = l & 15, lq = l >> 4;
  const size_t m0 = (size_t)blockIdx.x * 128;
  const int n0 = blockIdx.y * 128;
  const int r = tid >> 1;             // staging row 0..127
  const int sb = (tid & 1) << 1;      // staging slot base (16B slots): 0 or 2
  f32x4 acc[4][4] = {};

  for (int kt = 0; kt < 16; ++kt) {
    const int k0 = kt << 5;
    // stage A tile
    {
      char* dst = (char*)Al + r * 64;
      if (A_F32) {
        const float* A = (const float*)Ap + (m0 + r) * 512 + k0 + (sb << 3);
#pragma unroll
        for (int j = 0; j < 2; ++j) {
          float4 v0 = ((const float4*)A)[2 * j + 0];
          float4 v1 = ((const float4*)A)[2 * j + 1];
          short8 o;
          o[0] = (short)f2b(v0.x); o[1] = (short)f2b(v0.y);
          o[2] = (short)f2b(v0.z); o[3] = (short)f2b(v0.w);
          o[4] = (short)f2b(v1.x); o[5] = (short)f2b(v1.y);
          o[6] = (short)f2b(v1.z); o[7] = (short)f2b(v1.w);
          *(short8*)(dst + (((sb + j + (r >> 1)) & 3) << 4)) = o;
        }
      } else {
        const unsigned short* A =
            (const unsigned short*)Ap + (m0 + r) * 512 + k0 + (sb << 3);
#pragma unroll
        for (int j = 0; j < 2; ++j)
          *(short8*)(dst + (((sb + j + (r >> 1)) & 3) << 4)) =
              *(const short8*)(A + 8 * j);
      }
      // stage W tile
      const unsigned short* Wp = W + ((size_t)(n0 + r) << 9) + k0 + (sb << 3);
      char* dstB = (char*)Bl + r * 64;
#pragma unroll
      for (int j = 0; j < 2; ++j)
        *(short8*)(dstB + (((sb + j + (r >> 1)) & 3) << 4)) =
            *(const short8*)(Wp + 8 * j);
    }
    __syncthreads();
    short8 af[4], bf[4];
#pragma unroll
    for (int i = 0; i < 4; ++i) {
      int row = wr * 64 + i * 16 + lm;
      af[i] = *(const short8*)((char*)Al + row * 64 +
                               (((lq + (row >> 1)) & 3) << 4));
    }
#pragma unroll
    for (int j = 0; j < 4; ++j) {
      int row = wc * 64 + j * 16 + lm;
      bf[j] = *(const short8*)((char*)Bl + row * 64 +
                               (((lq + (row >> 1)) & 3) << 4));
    }
#pragma unroll
    for (int i = 0; i < 4; ++i)
#pragma unroll
      for (int j = 0; j < 4; ++j)
        acc[i][j] =
            __builtin_amdgcn_mfma_f32_16x16x32_bf16(af[i], bf[j], acc[i][j], 0, 0, 0);
    __syncthreads();
  }
  float bv[4];
#pragma unroll
  for (int j = 0; j < 4; ++j) bv[j] = bias[n0 + wc * 64 + j * 16 + lm];
#pragma unroll
  for (int i = 0; i < 4; ++i) {
#pragma unroll
    for (int r4 = 0; r4 < 4; ++r4) {
      size_t gm = m0 + wr * 64 + i * 16 + lq * 4 + r4;
#pragma unroll
      for (int j = 0; j < 4; ++j) {
        int gn = n0 + wc * 64 + j * 16 + lm;
        float v = acc[i][j][r4] + bv[j];
        if (OUT_BF16)
          ((unsigned short*)Cp)[(gm << 9) + gn] = f2b(v);
        else
          ((float*)Cp)[(gm << 9) + gn] = v;
      }
    }
  }
}

// ---------------- recurrence (M=1, i8 MFMA, single-row A, shfl epilogue) ---
// block g: batch row g. wave w: cols [64w,64w+64) = 4 j-tiles; weights
// bregs[8][4] (AGPR-resident, MFMA-native). As[2][512] i8: only lm==0 lanes
// read (A row 0); rows 1..15 fed zeros. acc[j][0] (lq==0 lanes) pulled to
// all lanes via __shfl; epilogue 1 col/lane (n = tid), coalesced stores.
__global__ __launch_bounds__(512, 1) void recur16_kernel(
    const unsigned short* __restrict__ ig,   // (T*B,512) bf16 plain
    const float* __restrict__ ei,            // (T,512) f32 plain
    const char* __restrict__ wrec8,          // (H,H) i8
    const float* __restrict__ wscale,        // (H)
    const float* __restrict__ rbias,         // (H)
    unsigned short* __restrict__ hs,         // (T*B,512) bf16 plain
    float* __restrict__ h_last) {            // (B,H) f32
  __shared__ __align__(16) char As[2][512];  // 1 KB
  const int tid = threadIdx.x;
  const int g = blockIdx.x;            // batch row
  const int w = tid >> 6, l = tid & 63;
  const int lm = l & 15, lq = l >> 4;
  const int nbase = w << 6;
  const int n_own = nbase + l;         // == tid; this lane's output column
  const bool lmz = (lm == 0);

  // weights: bregs[kk][j] = Wrec8[nbase+j*16+lm][kk*64+lq*16 .. +16]
  int4x bregs[8][4];
#pragma unroll
  for (int kk = 0; kk < 8; ++kk)
#pragma unroll
    for (int j = 0; j < 4; ++j)
      bregs[kk][j] = *(const int4x*)(
          wrec8 + ((size_t)(nbase + j * 16 + lm) << 9) + (kk << 6) + (lq << 4));
  const float wscv = wscale[n_own] * 0.0625f;   // * (1/16) a-scale
  const float rbv  = rbias[n_own];
  // zero both As parities (h0 = 0)
  if (tid < 256) ((int*)As)[tid] = 0;
  __syncthreads();

  // register double-buffer of ig[t] / ei[t+1]
  const unsigned short* igp = ig + ((size_t)g << 9) + n_own; // t-stride 65536
  unsigned short ig_cur = igp[0];
  float ei_cur = ei[512 + n_own];

#pragma unroll 1
  for (int t = 0; t < 512; ++t) {
    const int par = t & 1, par2 = par ^ 1;
    // prefetch next step (consumed next iteration; hides under MFMAs)
    unsigned short ig_nxt = 0;
    float ei_nxt = 0.f;
    if (t < 511)
      ig_nxt = __builtin_nontemporal_load(igp + (size_t)(t + 1) * 65536);
    if (t < 510) ei_nxt = ei[(size_t)(t + 2) * 512 + n_own];

    // K-loop: A row 0 = a_t, rows 1..15 zero. 4 chains of 8.
    int4x acc[4] = {};
    const char* ap = &As[par][0];
#pragma unroll
    for (int kk = 0; kk < 8; ++kk) {
      int4x av = {0, 0, 0, 0};
      if (lmz)
        av = *(const int4x*)(ap + (kk << 6) + (lq << 4));
#pragma unroll
      for (int j = 0; j < 4; ++j)
        acc[j] = __builtin_amdgcn_mfma_i32_16x16x64_i8(av, bregs[kk][j],
                                                       acc[j], 0, 0, 0);
    }
    // redistribute via shuffle: lane l needs acc[l>>4][0] from lane (l&15)
    const int s0 = __shfl(acc[0][0], lm);
    const int s1 = __shfl(acc[1][0], lm);
    const int s2 = __shfl(acc[2][0], lm);
    const int s3 = __shfl(acc[3][0], lm);
    const int lo = (lq & 1) ? s1 : s0;
    const int hi = (lq & 1) ? s3 : s2;
    const int acci = (lq & 2) ? hi : lo;

    float z = (float)acci * wscv + b2f(ig_cur) + rbv;
    // fast softplus: max(z,0) + log(1+exp(-|z|)), native exp/log
    float az = fabsf(z);
    float h = fmaxf(z, 0.f) + __logf(1.f + __expf(-az));
    if (t < 511) {
      float a = h * ei_cur * 16.f;
      int ai = (int)rintf(fminf(fmaxf(a, -127.f), 127.f));
      As[par2][n_own] = (char)ai;   // coalesced byte store
    }
    __builtin_nontemporal_store(f2b(h),
                                hs + (((size_t)t * 128 + g) << 9) + n_own);
    if (t == 511) h_last[((size_t)g << 9) + n_own] = h;
    ig_cur = ig_nxt;
    ei_cur = ei_nxt;
    __syncthreads();   // As[par2] visible before next step's K-loop
  }
}

// ---------------- launch ---------------------------------------------------
extern "C" void kernel_launch(void* const* d_in, const int* in_sizes, int n_in,
                              void* d_out, int out_size, void* d_ws,
                              size_t ws_size, hipStream_t stream) {
  const float* x     = (const float*)d_in[0];
  const float* gu    = (const float*)d_in[1];
  const float* Win   = (const float*)d_in[2];
  const float* bin   = (const float*)d_in[3];
  const float* Wrec  = (const float*)d_in[4];
  const float* rbias = (const float*)d_in[5];
  const float* elog  = (const float*)d_in[6];
  const float* Wout  = (const float*)d_in[7];
  const float* bout  = (const float*)d_in[8];

  char* ws = (char*)d_ws;
  float* ei             = (float*)ws;                        // 1 MB
  unsigned short* winb  = (unsigned short*)(ws + 4194304);   // 512 KB
  unsigned short* woutb = (unsigned short*)(ws + 4718592);   // 512 KB
  char* wrec8           = (char*)(ws + 5242880);             // 256 KB
  float* wscale         = (float*)(ws + 5505024);            // 2 KB
  unsigned short* igb   = (unsigned short*)(ws + 6291456);   // 64 MB
  unsigned short* hs    = (unsigned short*)(ws + 73400320);  // 64 MB

  float* outp  = (float*)d_out;            // (T,B,O) f32
  float* hlast = outp + 33554432;          // (B,H)
  float* clast = outp + 33554432 + 65536;  // (B,H) zeros

  prep_kernel<<<1024, 256, 0, stream>>>(gu, elog, Win, Wout, ei, winb, woutb,
                                        clast);
  wquant_kernel<<<512, 64, 0, stream>>>(Wrec, wrec8, wscale);
  gemm512<1, 1><<<dim3(512, 4), 256, 0, stream>>>(x, winb, bin, igb);
  recur16_kernel<<<128, 512, 0, stream>>>(igb, ei, wrec8, wscale, rbias, hs,
                                          hlast);
  gemm512<0, 0><<<dim3(512, 4), 256, 0, stream>>>(hs, woutb, bout, outp);
}